// Round 5
// baseline (27091.357 us; speedup 1.0000x reference)
//
#include <hip/hip_runtime.h>

#define T_N 512
#define B_N 32
#define H_N 512
#define G3 1536
#define NBLK 192
#define NGRP 8
#define GRPSZ (NBLK / NGRP)     // 24
#define NT 1024
#define EPS_LN 1e-5f
#define OUT_HID_OFF (T_N * B_N * 1024)

// ws layout (floats):
//  [0..320)     barrier: 8 group counters (32-float spacing) + top + release
//  [320)        stats ring: 4 slots x (4 kd x 3 g x 32 b x 2) = 4 x 768
//  [3392)       axd ring:   3 slots x [2 d][32 b][1536 j]   (ax for step s in slot s%3)
//  [298304)     ahd ring:   2 slots x [2 d][32 b][1536 j]   (ah for step s in slot s&1)
//  [494912)     y0: [2 d][512 t][32 b][512]  (cstore ph0, plain-read ph1)
#define WS_STATS 320
#define STSLOT   768
#define WS_AXD   (WS_STATS + 4 * STSLOT)
#define DSLOT    (2 * B_N * G3)
#define WS_AHD   (WS_AXD + 3 * DSLOT)
#define WS_Y0    (WS_AHD + 2 * DSLOT)

// LDS (dynamic, 163072 B — baseline-proven size):
//  wlds: 126 k4 x 64 j x 4 = 32256 floats (k = 0..503)
//  hl:   16 b x 516        =  8256 floats (block-LOCAL h state; k-padded)
//  sred: 256 floats ([b_loc 16][jq 2][st 2] used)
#define WLDS_F 32256
#define HL_F   8256
#define LDS_BYTES ((WLDS_F + HL_F + 256) * 4)

__device__ __forceinline__ float cload(const float* p) {
  return __hip_atomic_load(p, __ATOMIC_RELAXED, __HIP_MEMORY_SCOPE_AGENT);
}
__device__ __forceinline__ void cstore(float* p, float v) {
  __hip_atomic_store(p, v, __ATOMIC_RELAXED, __HIP_MEMORY_SCOPE_AGENT);
}

// Hierarchical fence-free grid barrier (baseline-proven).
__device__ __forceinline__ void gbar(unsigned* barbase, unsigned& epoch, int grp) {
  epoch++;
  __builtin_amdgcn_s_waitcnt(0);   // drain my vmem: coherent stores at L3
  __syncthreads();
  if (threadIdx.x == 0) {
    unsigned* gc  = barbase + grp * 32;
    unsigned* top = barbase + NGRP * 32;
    unsigned* rel = barbase + NGRP * 32 + 32;
    unsigned r = __hip_atomic_fetch_add(gc, 1u, __ATOMIC_RELAXED, __HIP_MEMORY_SCOPE_AGENT);
    if (r == epoch * GRPSZ - 1u) {
      unsigned r2 = __hip_atomic_fetch_add(top, 1u, __ATOMIC_RELAXED, __HIP_MEMORY_SCOPE_AGENT);
      if (r2 == epoch * NGRP - 1u)
        __hip_atomic_store(rel, epoch, __ATOMIC_RELAXED, __HIP_MEMORY_SCOPE_AGENT);
    }
    while (__hip_atomic_load(rel, __ATOMIC_RELAXED, __HIP_MEMORY_SCOPE_AGENT) < epoch)
      __builtin_amdgcn_s_sleep(1);
  }
  __syncthreads();
}

// 8 FMAs: one j-column weight W against 2 b-rows (R1,R2), componentwise.
#define FMA_M(M, W, R1, R2) do { \
  acc[M][0][0]=fmaf((R1).x,(W).x,acc[M][0][0]); acc[M][0][1]=fmaf((R1).y,(W).y,acc[M][0][1]); \
  acc[M][0][2]=fmaf((R1).z,(W).z,acc[M][0][2]); acc[M][0][3]=fmaf((R1).w,(W).w,acc[M][0][3]); \
  acc[M][1][0]=fmaf((R2).x,(W).x,acc[M][1][0]); acc[M][1][1]=fmaf((R2).y,(W).y,acc[M][1][1]); \
  acc[M][1][2]=fmaf((R2).z,(W).z,acc[M][1][2]); acc[M][1][3]=fmaf((R2).w,(W).w,acc[M][1][3]); \
} while (0)

__global__ void __launch_bounds__(NT, 1)
lngru10(const float* __restrict__ x, const float* __restrict__ h0,
        const float* __restrict__ Wx, const float* __restrict__ Wh,
        const float* __restrict__ bx, const float* __restrict__ bh,
        const float* __restrict__ gx, const float* __restrict__ bex,
        const float* __restrict__ gh, const float* __restrict__ beh,
        float* __restrict__ out, float* __restrict__ ws)
{
  extern __shared__ __align__(16) float smem[];
  float* wlds = smem;                    // [k4 126][j 64][4]
  float* hl   = smem + WLDS_F;           // [b 16][516]  (local h state)
  float* sred = smem + WLDS_F + HL_F;    // [b_loc 16][jq 2][st 2]

  unsigned* barbase = (unsigned*)ws;
  float* stats = ws + WS_STATS;
  float* axd   = ws + WS_AXD;
  float* ahd   = ws + WS_AHD;
  float* y0    = ws + WS_Y0;

  const int tid  = threadIdx.x;
  const int lane = tid & 63;
  const int wv   = tid >> 6;              // 16 waves
  const int bid  = blockIdx.x;
  const int grp  = bid & 7;
  const int bs   = bid & 1;               // b-half
  const int jt   = (bid >> 1) % 24;       // 64-wide j tile
  const int kd   = (bid >> 1) / 24;       // d*2 + kind
  const int kind = kd & 1;                // 0: ax, 1: ah
  const int d    = kd >> 1;
  const int j0   = jt * 64;
  const int g    = jt >> 3;               // gate of this j-tile
  const int b0   = bs * 16;
  const bool writer = (kind == 1) && (jt == 0);   // y0/out/hT writer

  // GEMM: 2 waves (wv<2); lane = (boct 8)x(jj 8); lane tile 4j x 2b:
  //   j_local = jq*32 + m*8 + jj (m=0..3), b_local = boct, boct+8. Full K.
  const bool gw  = (wv < 2);
  const int jq   = wv & 1;
  const int jj   = lane & 7;
  const int boct = lane >> 3;

  unsigned epoch = 0;

  for (int ph = 0; ph < 2; ++ph) {
    const int widx = ph * 2 + d;

    gbar(barbase, epoch, grp);   // phase entry: prior phase's y0/out drained

    // ---- stage weights: k<504 -> LDS, k>=504 -> gw-lane tail regs ----
    const float* wgl = (kind ? Wh : Wx) + (size_t)widx * H_N * G3 + j0;
    for (int kk = 0; kk < 32; ++kk) {
      int k = wv * 32 + kk;
      if (k < 504)
        wlds[(k >> 2) * 256 + lane * 4 + (k & 3)] = wgl[(size_t)k * G3 + lane];
    }
    float4 wt[4][2];
    float  bva[4];
    if (gw) {
#pragma unroll
      for (int m = 0; m < 4; ++m) {
        const int jl = jq * 32 + m * 8 + jj;
        bva[m] = (kind ? bh : bx)[widx * G3 + j0 + jl];
#pragma unroll
        for (int h = 0; h < 2; ++h) {
          wt[m][h].x = wgl[(size_t)(504 + 4*h + 0) * G3 + jl];
          wt[m][h].y = wgl[(size_t)(504 + 4*h + 1) * G3 + jl];
          wt[m][h].z = wgl[(size_t)(504 + 4*h + 2) * G3 + jl];
          wt[m][h].w = wgl[(size_t)(504 + 4*h + 3) * G3 + jl];
        }
      }
    }
    if (kind) {   // local h state <- h0 (row local i <-> global b0+i)
#pragma unroll
      for (int q = 0; q < 8; ++q)
        hl[wv * 516 + lane + 64*q] =
            h0[((size_t)widx * B_N + b0 + wv) * H_N + lane + 64*q];
    }
    __syncthreads();

    const float* xsrc = (ph == 0) ? x : (y0 + (size_t)d * T_N * B_N * H_N);
    const float4* wbase = (const float4*)wlds + jq * 32 + jj;

    // GEMM + dots + stats for step-index ss (kind0: ax(ss); kind1: ah(ss))
    auto run_step = [&](int ss) {
      float acc[4][2][4] = {};
      if (gw) {
        if (kind) {
          const float* h1 = hl + boct * 516;
          const float* h2 = h1 + 8 * 516;
#pragma unroll 3
          for (int k4 = 0; k4 < 126; ++k4) {
            float4 w0 = wbase[k4*64 + 0];
            float4 w1 = wbase[k4*64 + 8];
            float4 w2 = wbase[k4*64 + 16];
            float4 w3 = wbase[k4*64 + 24];
            float4 r1 = *(const float4*)(h1 + k4*4);
            float4 r2 = *(const float4*)(h2 + k4*4);
            FMA_M(0,w0,r1,r2); FMA_M(1,w1,r1,r2);
            FMA_M(2,w2,r1,r2); FMA_M(3,w3,r1,r2);
          }
          float4 r1a = *(const float4*)(h1 + 504);
          float4 r1b = *(const float4*)(h1 + 508);
          float4 r2a = *(const float4*)(h2 + 504);
          float4 r2b = *(const float4*)(h2 + 508);
          FMA_M(0,wt[0][0],r1a,r2a); FMA_M(1,wt[1][0],r1a,r2a);
          FMA_M(2,wt[2][0],r1a,r2a); FMA_M(3,wt[3][0],r1a,r2a);
          FMA_M(0,wt[0][1],r1b,r2b); FMA_M(1,wt[1][1],r1b,r2b);
          FMA_M(2,wt[2][1],r1b,r2b); FMA_M(3,wt[3][1],r1b,r2b);
        } else {
          const int t = d ? (T_N - 1 - ss) : ss;
          const float* rp1 = xsrc + ((size_t)t * B_N + b0 + boct) * H_N;
          const float* rp2 = rp1 + 8 * H_N;
#pragma unroll 4
          for (int k4 = 0; k4 < 126; ++k4) {
            float4 w0 = wbase[k4*64 + 0];
            float4 w1 = wbase[k4*64 + 8];
            float4 w2 = wbase[k4*64 + 16];
            float4 w3 = wbase[k4*64 + 24];
            float4 r1 = *(const float4*)(rp1 + k4*4);
            float4 r2 = *(const float4*)(rp2 + k4*4);
            FMA_M(0,w0,r1,r2); FMA_M(1,w1,r1,r2);
            FMA_M(2,w2,r1,r2); FMA_M(3,w3,r1,r2);
          }
          float4 r1a = *(const float4*)(rp1 + 504);
          float4 r1b = *(const float4*)(rp1 + 508);
          float4 r2a = *(const float4*)(rp2 + 504);
          float4 r2b = *(const float4*)(rp2 + 508);
          FMA_M(0,wt[0][0],r1a,r2a); FMA_M(1,wt[1][0],r1a,r2a);
          FMA_M(2,wt[2][0],r1a,r2a); FMA_M(3,wt[3][0],r1a,r2a);
          FMA_M(0,wt[0][1],r1b,r2b); FMA_M(1,wt[1][1],r1b,r2b);
          FMA_M(2,wt[2][1],r1b,r2b); FMA_M(3,wt[3][1],r1b,r2b);
        }
      }
      float* dd  = kind ? (ahd + (ss & 1) * DSLOT) : (axd + (ss % 3) * DSLOT);
      float* stp = stats + (ss & 3) * STSLOT;
      if (gw) {
        float* dr1 = dd + (size_t)(d * B_N + b0 + boct) * G3 + j0;
        float* dr2 = dr1 + (size_t)8 * G3;
        float s1a = 0.f, s2a = 0.f, s1b = 0.f, s2b = 0.f;
#pragma unroll
        for (int m = 0; m < 4; ++m) {
          const int jl = jq * 32 + m * 8 + jj;
          float t1 = bva[m] + ((acc[m][0][0]+acc[m][0][1]) + (acc[m][0][2]+acc[m][0][3]));
          float t2 = bva[m] + ((acc[m][1][0]+acc[m][1][1]) + (acc[m][1][2]+acc[m][1][3]));
          cstore(dr1 + jl, t1);
          cstore(dr2 + jl, t2);
          s1a += t1; s2a += t1 * t1; s1b += t2; s2b += t2 * t2;
        }
        s1a += __shfl_xor(s1a, 1, 64); s2a += __shfl_xor(s2a, 1, 64);
        s1b += __shfl_xor(s1b, 1, 64); s2b += __shfl_xor(s2b, 1, 64);
        s1a += __shfl_xor(s1a, 2, 64); s2a += __shfl_xor(s2a, 2, 64);
        s1b += __shfl_xor(s1b, 2, 64); s2b += __shfl_xor(s2b, 2, 64);
        s1a += __shfl_xor(s1a, 4, 64); s2a += __shfl_xor(s2a, 4, 64);
        s1b += __shfl_xor(s1b, 4, 64); s2b += __shfl_xor(s2b, 4, 64);
        if (jj == 0) {
          sred[boct * 4 + jq * 2 + 0] = s1a;
          sred[boct * 4 + jq * 2 + 1] = s2a;
          sred[(boct + 8) * 4 + jq * 2 + 0] = s1b;
          sred[(boct + 8) * 4 + jq * 2 + 1] = s2b;
        }
      }
      __syncthreads();
      if (tid < 32) {
        int bl = tid >> 1, st = tid & 1;
        float a2 = sred[bl * 4 + st] + sred[bl * 4 + 2 + st];
        atomicAdd(&stp[((kd * 3 + g) * B_N + b0 + bl) * 2 + st], a2);
      }
    };

    if (!kind) run_step(0);       // prologue: ax(step 0) -> slot 0, stats slot 0
    gbar(barbase, epoch, grp);

    for (int s = 0; s < T_N; ++s) {
      // window s (pre-barrier): kind1 -> ah(s); kind0 -> ax(s+1)
      if (kind) run_step(s);
      else if (s < T_N - 1) run_step(s + 1);

      if (bid == NBLK - 1) {      // zero stats slot (s+2)%4: free this window
        float* so = stats + ((s + 2) & 3) * STSLOT;
        if (tid < 768) cstore(so + tid, 0.f);
      }

      gbar(barbase, epoch, grp);  // the ONLY barrier per step

      // window s+1 (post-barrier): kind1 computes gates(s) locally
      if (kind) {
        const int t  = d ? (T_N - 1 - s) : s;
        const int gb = b0 + wv;
        const float* axr = axd + (s % 3) * DSLOT + (size_t)(d * B_N + gb) * G3;
        const float* ahr = ahd + (s & 1) * DSLOT + (size_t)(d * B_N + gb) * G3;
        const float* stp = stats + (s & 3) * STSLOT;
        float mu[2][3], inv[2][3];
#pragma unroll
        for (int k2 = 0; k2 < 2; ++k2)
#pragma unroll
          for (int g2 = 0; g2 < 3; ++g2) {
            const float* sl = stp + (((d * 2 + k2) * 3 + g2) * B_N + gb) * 2;
            float m1 = cload(sl)     * (1.f / 512.f);
            float m2 = cload(sl + 1) * (1.f / 512.f);
            mu[k2][g2]  = m1;
            inv[k2][g2] = rsqrtf(m2 - m1 * m1 + EPS_LN);
          }
        const float* gxr = gx  + widx * G3;
        const float* bxr = bex + widx * G3;
        const float* ghr = gh  + widx * G3;
        const float* bhr = beh + widx * G3;
#pragma unroll 2
        for (int q = 0; q < 8; ++q) {
          const int c = lane + 64 * q;
          float ax0 = cload(axr + c);
          float ax1 = cload(axr + H_N + c);
          float ax2 = cload(axr + 2 * H_N + c);
          float ah0 = cload(ahr + c);
          float ah1 = cload(ahr + H_N + c);
          float ah2 = cload(ahr + 2 * H_N + c);
          float a00 = (ax0 - mu[0][0]) * inv[0][0] * gxr[c]           + bxr[c];
          float a01 = (ax1 - mu[0][1]) * inv[0][1] * gxr[H_N + c]     + bxr[H_N + c];
          float a02 = (ax2 - mu[0][2]) * inv[0][2] * gxr[2*H_N + c]   + bxr[2*H_N + c];
          float a10 = (ah0 - mu[1][0]) * inv[1][0] * ghr[c]           + bhr[c];
          float a11 = (ah1 - mu[1][1]) * inv[1][1] * ghr[H_N + c]     + bhr[H_N + c];
          float a12 = (ah2 - mu[1][2]) * inv[1][2] * ghr[2*H_N + c]   + bhr[2*H_N + c];
          float r = 1.f / (1.f + __expf(-(a00 + a10)));
          float z = 1.f / (1.f + __expf(-(a01 + a11)));
          float n = tanhf(a02 + r * a12);
          float* hp = hl + wv * 516 + c;
          float hnew = (1.f - z) * n + z * *hp;
          *hp = hnew;
          if (writer) {
            if (ph == 0)
              cstore(&y0[(((size_t)d * T_N + t) * B_N + gb) * H_N + c], hnew);
            else
              out[((size_t)t * B_N + gb) * 1024 + d * H_N + c] = hnew;
            if (s == T_N - 1)
              out[OUT_HID_OFF + ((size_t)widx * B_N + gb) * H_N + c] = hnew;
          }
        }
        __syncthreads();   // h(s) in hl ready for GEMM(s+1)
      }
    }
  }
}

extern "C" void kernel_launch(void* const* d_in, const int* in_sizes, int n_in,
                              void* d_out, int out_size, void* d_ws, size_t ws_size,
                              hipStream_t stream) {
  const float* x    = (const float*)d_in[0];
  const float* h0   = (const float*)d_in[1];
  const float* Wx   = (const float*)d_in[2];
  const float* Wh   = (const float*)d_in[3];
  const float* bxp  = (const float*)d_in[4];
  const float* bhp  = (const float*)d_in[5];
  const float* gxp  = (const float*)d_in[6];
  const float* bexp = (const float*)d_in[7];
  const float* ghp  = (const float*)d_in[8];
  const float* behp = (const float*)d_in[9];
  float* out = (float*)d_out;
  float* ws  = (float*)d_ws;

  hipMemsetAsync(d_ws, 0, 16384, stream);   // barrier lines + 4-deep stats ring

  hipFuncSetAttribute((const void*)lngru10,
                      hipFuncAttributeMaxDynamicSharedMemorySize, LDS_BYTES);

  void* args[] = {(void*)&x, (void*)&h0, (void*)&Wx, (void*)&Wh, (void*)&bxp, (void*)&bhp,
                  (void*)&gxp, (void*)&bexp, (void*)&ghp, (void*)&behp, (void*)&out, (void*)&ws};
  hipLaunchCooperativeKernel((void*)lngru10, dim3(NBLK), dim3(NT), args, LDS_BYTES, stream);
}

// Round 6
// 25299.602 us; speedup vs baseline: 1.0708x; 1.0708x over previous
//
#include <hip/hip_runtime.h>

#define T_N 512
#define B_N 32
#define H_N 512
#define G3 1536
#define NBLK 192
#define NGRP 8
#define GRPSZ (NBLK / NGRP)     // 24
#define NT 1024
#define EPS_LN 1e-5f
#define OUT_HID_OFF (T_N * B_N * 1024)

// ws layout (floats):
//  [0..832)     barriers: B1 lines (8 grp x 32) + top(256) + rel(288);
//               B2 at +320: lines (8 grp x 32) + top(576) + rel(608)
//  [832)        stats ring: 4 slots x (4 kd x 3 g x 32 b x 2) = 3072
//  [3904)       axd ring: 2 slots x [2 d][32 b][1536 j]
//  [200512)     ahd ring: 2 slots x [2 d][32 b][1536 j]
//  [397120)     hbuf: [2 d][32 b][512]  (gates RMW own cells; kind1 stages)
//  [429888)     y0: [2 d][512 t][32 b][512]
#define WS_STATS 832
#define STSLOT   768
#define WS_AXD   (WS_STATS + 4 * STSLOT)
#define DSLOT    (2 * B_N * G3)
#define WS_AHD   (WS_AXD + 2 * DSLOT)
#define WS_HBUF  (WS_AHD + 2 * DSLOT)
#define WS_Y0    (WS_HBUF + 2 * B_N * H_N)

// LDS (163072 B — proven): wlds 32256, hl 8256, sred 256
#define WLDS_F 32256
#define HL_F   8256
#define LDS_BYTES ((WLDS_F + HL_F + 256) * 4)

__device__ __forceinline__ float cload(const float* p) {
  return __hip_atomic_load(p, __ATOMIC_RELAXED, __HIP_MEMORY_SCOPE_AGENT);
}
__device__ __forceinline__ void cstore(float* p, float v) {
  __hip_atomic_store(p, v, __ATOMIC_RELAXED, __HIP_MEMORY_SCOPE_AGENT);
}
union U64F2 { unsigned long long u; float f[2]; };
__device__ __forceinline__ U64F2 cload2(const float* p) {
  U64F2 r;
  r.u = __hip_atomic_load((const unsigned long long*)p, __ATOMIC_RELAXED,
                          __HIP_MEMORY_SCOPE_AGENT);
  return r;
}

// Full hierarchical barrier over all 192 blocks (proven).
__device__ __forceinline__ void gbar(unsigned* barbase, unsigned& epoch, int grp) {
  epoch++;
  __builtin_amdgcn_s_waitcnt(0);
  __syncthreads();
  if (threadIdx.x == 0) {
    unsigned* gc  = barbase + grp * 32;
    unsigned* top = barbase + 256;
    unsigned* rel = barbase + 288;
    unsigned r = __hip_atomic_fetch_add(gc, 1u, __ATOMIC_RELAXED, __HIP_MEMORY_SCOPE_AGENT);
    if (r == epoch * GRPSZ - 1u) {
      unsigned r2 = __hip_atomic_fetch_add(top, 1u, __ATOMIC_RELAXED, __HIP_MEMORY_SCOPE_AGENT);
      if (r2 == epoch * NGRP - 1u)
        __hip_atomic_store(rel, epoch, __ATOMIC_RELAXED, __HIP_MEMORY_SCOPE_AGENT);
    }
    while (__hip_atomic_load(rel, __ATOMIC_RELAXED, __HIP_MEMORY_SCOPE_AGENT) < epoch)
      __builtin_amdgcn_s_sleep(1);
  }
  __syncthreads();
}

// Producer-publish: 32 gate blocks arrive (4 per bid&7 group), no spin.
__device__ __forceinline__ void gbar2_arrive(unsigned* b2, unsigned& e2, int grp) {
  e2++;
  __builtin_amdgcn_s_waitcnt(0);   // drain h/y0/out stores
  __syncthreads();
  if (threadIdx.x == 0) {
    unsigned r = __hip_atomic_fetch_add(b2 + grp * 32, 1u, __ATOMIC_RELAXED, __HIP_MEMORY_SCOPE_AGENT);
    if (r == e2 * 4u - 1u) {
      unsigned r2 = __hip_atomic_fetch_add(b2 + 256, 1u, __ATOMIC_RELAXED, __HIP_MEMORY_SCOPE_AGENT);
      if (r2 == e2 * 8u - 1u)
        __hip_atomic_store(b2 + 288, e2, __ATOMIC_RELAXED, __HIP_MEMORY_SCOPE_AGENT);
    }
  }
}

// Consumer wait on the publish flag (no arrival).
__device__ __forceinline__ void gbar2_wait(unsigned* b2, unsigned& e2) {
  e2++;
  if (threadIdx.x == 0) {
    while (__hip_atomic_load(b2 + 288, __ATOMIC_RELAXED, __HIP_MEMORY_SCOPE_AGENT) < e2)
      __builtin_amdgcn_s_sleep(1);
  }
  __syncthreads();
}

// 8 FMAs: one j-column weight W against 2 b-rows (R1,R2), componentwise.
#define FMA_M(M, W, R1, R2) do { \
  acc[M][0][0]=fmaf((R1).x,(W).x,acc[M][0][0]); acc[M][0][1]=fmaf((R1).y,(W).y,acc[M][0][1]); \
  acc[M][0][2]=fmaf((R1).z,(W).z,acc[M][0][2]); acc[M][0][3]=fmaf((R1).w,(W).w,acc[M][0][3]); \
  acc[M][1][0]=fmaf((R2).x,(W).x,acc[M][1][0]); acc[M][1][1]=fmaf((R2).y,(W).y,acc[M][1][1]); \
  acc[M][1][2]=fmaf((R2).z,(W).z,acc[M][1][2]); acc[M][1][3]=fmaf((R2).w,(W).w,acc[M][1][3]); \
} while (0)

__global__ void __launch_bounds__(NT, 1)
lngru11(const float* __restrict__ x, const float* __restrict__ h0,
        const float* __restrict__ Wx, const float* __restrict__ Wh,
        const float* __restrict__ bx, const float* __restrict__ bh,
        const float* __restrict__ gx, const float* __restrict__ bex,
        const float* __restrict__ gh, const float* __restrict__ beh,
        float* __restrict__ out, float* __restrict__ ws)
{
  extern __shared__ __align__(16) float smem[];
  float* wlds = smem;                    // [k4 126][j 64][4]
  float* hl   = smem + WLDS_F;           // [b 16][516]
  float* sred = smem + WLDS_F + HL_F;    // [b_loc 16][jq 2][st 2]

  unsigned* barbase  = (unsigned*)ws;
  unsigned* barbase2 = barbase + 320;
  float* stats = ws + WS_STATS;
  float* axd   = ws + WS_AXD;
  float* ahd   = ws + WS_AHD;
  float* hbuf  = ws + WS_HBUF;
  float* y0    = ws + WS_Y0;

  const int tid  = threadIdx.x;
  const int lane = tid & 63;
  const int wv   = tid >> 6;              // 16 waves
  const int bid  = blockIdx.x;
  const int grp  = bid & 7;
  const int bs   = bid & 1;               // b-half
  const int jt   = (bid >> 1) % 24;       // 64-wide j tile
  const int kd   = (bid >> 1) / 24;       // d*2 + kind
  const int kind = kd & 1;                // 0: ax, 1: ah
  const int d    = kd >> 1;
  const int j0   = jt * 64;
  const int g    = jt >> 3;               // gate of this j-tile
  const int b0   = bs * 16;
  const bool is_gate = (kind == 0) && (jt < 8);   // 32 gate blocks

  // GEMM: 2 waves (wv<2); lane = (boct 8)x(jj 8); lane tile 4j x 2b.
  const bool gw  = (wv < 2);
  const int jq   = wv & 1;
  const int jj   = lane & 7;
  const int boct = lane >> 3;

  unsigned epoch = 0, epoch2 = 0;

  for (int ph = 0; ph < 2; ++ph) {
    const int widx = ph * 2 + d;

    gbar(barbase, epoch, grp);   // phase entry (y0 of prior phase drained)

    // ---- stage weights: k<504 -> LDS, k>=504 -> gw-lane tail regs ----
    const float* wgl = (kind ? Wh : Wx) + (size_t)widx * H_N * G3 + j0;
    for (int kk = 0; kk < 32; ++kk) {
      int k = wv * 32 + kk;
      if (k < 504)
        wlds[(k >> 2) * 256 + lane * 4 + (k & 3)] = wgl[(size_t)k * G3 + lane];
    }
    float4 wt[4][2];
    float  bva[4];
    if (gw) {
#pragma unroll
      for (int m = 0; m < 4; ++m) {
        const int jl = jq * 32 + m * 8 + jj;
        bva[m] = (kind ? bh : bx)[widx * G3 + j0 + jl];
#pragma unroll
        for (int h = 0; h < 2; ++h) {
          wt[m][h].x = wgl[(size_t)(504 + 4*h + 0) * G3 + jl];
          wt[m][h].y = wgl[(size_t)(504 + 4*h + 1) * G3 + jl];
          wt[m][h].z = wgl[(size_t)(504 + 4*h + 2) * G3 + jl];
          wt[m][h].w = wgl[(size_t)(504 + 4*h + 3) * G3 + jl];
        }
      }
    }
    if (kind) {   // local h state <- h0
#pragma unroll
      for (int q = 0; q < 8; ++q)
        hl[wv * 516 + lane + 64*q] =
            h0[((size_t)widx * B_N + b0 + wv) * H_N + lane + 64*q];
    }
    if (is_gate) {  // hbuf <- h0 for this block's cells (self-consumed)
      cstore(&hbuf[(d * B_N + b0 + wv) * H_N + j0 + lane],
             h0[((size_t)widx * B_N + b0 + wv) * H_N + j0 + lane]);
    }
    __syncthreads();

    const float* xsrc = (ph == 0) ? x : (y0 + (size_t)d * T_N * B_N * H_N);
    const float4* wbase = (const float4*)wlds + jq * 32 + jj;

    auto run_step = [&](int ss) {
      float acc[4][2][4] = {};
      if (gw) {
        if (kind) {
          const float* h1 = hl + boct * 516;
          const float* h2 = h1 + 8 * 516;
#pragma unroll 3
          for (int k4 = 0; k4 < 126; ++k4) {
            float4 w0 = wbase[k4*64 + 0];
            float4 w1 = wbase[k4*64 + 8];
            float4 w2 = wbase[k4*64 + 16];
            float4 w3 = wbase[k4*64 + 24];
            float4 r1 = *(const float4*)(h1 + k4*4);
            float4 r2 = *(const float4*)(h2 + k4*4);
            FMA_M(0,w0,r1,r2); FMA_M(1,w1,r1,r2);
            FMA_M(2,w2,r1,r2); FMA_M(3,w3,r1,r2);
          }
          float4 r1a = *(const float4*)(h1 + 504);
          float4 r1b = *(const float4*)(h1 + 508);
          float4 r2a = *(const float4*)(h2 + 504);
          float4 r2b = *(const float4*)(h2 + 508);
          FMA_M(0,wt[0][0],r1a,r2a); FMA_M(1,wt[1][0],r1a,r2a);
          FMA_M(2,wt[2][0],r1a,r2a); FMA_M(3,wt[3][0],r1a,r2a);
          FMA_M(0,wt[0][1],r1b,r2b); FMA_M(1,wt[1][1],r1b,r2b);
          FMA_M(2,wt[2][1],r1b,r2b); FMA_M(3,wt[3][1],r1b,r2b);
        } else {
          const int t = d ? (T_N - 1 - ss) : ss;
          const float* rp1 = xsrc + ((size_t)t * B_N + b0 + boct) * H_N;
          const float* rp2 = rp1 + 8 * H_N;
#pragma unroll 4
          for (int k4 = 0; k4 < 126; ++k4) {
            float4 w0 = wbase[k4*64 + 0];
            float4 w1 = wbase[k4*64 + 8];
            float4 w2 = wbase[k4*64 + 16];
            float4 w3 = wbase[k4*64 + 24];
            float4 r1 = *(const float4*)(rp1 + k4*4);
            float4 r2 = *(const float4*)(rp2 + k4*4);
            FMA_M(0,w0,r1,r2); FMA_M(1,w1,r1,r2);
            FMA_M(2,w2,r1,r2); FMA_M(3,w3,r1,r2);
          }
          float4 r1a = *(const float4*)(rp1 + 504);
          float4 r1b = *(const float4*)(rp1 + 508);
          float4 r2a = *(const float4*)(rp2 + 504);
          float4 r2b = *(const float4*)(rp2 + 508);
          FMA_M(0,wt[0][0],r1a,r2a); FMA_M(1,wt[1][0],r1a,r2a);
          FMA_M(2,wt[2][0],r1a,r2a); FMA_M(3,wt[3][0],r1a,r2a);
          FMA_M(0,wt[0][1],r1b,r2b); FMA_M(1,wt[1][1],r1b,r2b);
          FMA_M(2,wt[2][1],r1b,r2b); FMA_M(3,wt[3][1],r1b,r2b);
        }
      }
      float* dd  = (kind ? ahd : axd) + (ss & 1) * DSLOT;
      float* stp = stats + (ss & 3) * STSLOT;
      if (gw) {
        float* dr1 = dd + (size_t)(d * B_N + b0 + boct) * G3 + j0;
        float* dr2 = dr1 + (size_t)8 * G3;
        float s1a = 0.f, s2a = 0.f, s1b = 0.f, s2b = 0.f;
#pragma unroll
        for (int m = 0; m < 4; ++m) {
          const int jl = jq * 32 + m * 8 + jj;
          float t1 = bva[m] + ((acc[m][0][0]+acc[m][0][1]) + (acc[m][0][2]+acc[m][0][3]));
          float t2 = bva[m] + ((acc[m][1][0]+acc[m][1][1]) + (acc[m][1][2]+acc[m][1][3]));
          cstore(dr1 + jl, t1);
          cstore(dr2 + jl, t2);
          s1a += t1; s2a += t1 * t1; s1b += t2; s2b += t2 * t2;
        }
        s1a += __shfl_xor(s1a, 1, 64); s2a += __shfl_xor(s2a, 1, 64);
        s1b += __shfl_xor(s1b, 1, 64); s2b += __shfl_xor(s2b, 1, 64);
        s1a += __shfl_xor(s1a, 2, 64); s2a += __shfl_xor(s2a, 2, 64);
        s1b += __shfl_xor(s1b, 2, 64); s2b += __shfl_xor(s2b, 2, 64);
        s1a += __shfl_xor(s1a, 4, 64); s2a += __shfl_xor(s2a, 4, 64);
        s1b += __shfl_xor(s1b, 4, 64); s2b += __shfl_xor(s2b, 4, 64);
        if (jj == 0) {
          sred[boct * 4 + jq * 2 + 0] = s1a;
          sred[boct * 4 + jq * 2 + 1] = s2a;
          sred[(boct + 8) * 4 + jq * 2 + 0] = s1b;
          sred[(boct + 8) * 4 + jq * 2 + 1] = s2b;
        }
      }
      __syncthreads();
      if (tid < 32) {
        int bl = tid >> 1, st = tid & 1;
        float a2 = sred[bl * 4 + st] + sred[bl * 4 + 2 + st];
        atomicAdd(&stp[((kd * 3 + g) * B_N + b0 + bl) * 2 + st], a2);
      }
    };

    run_step(0);    // prologue: ax(0)/ah(0) -> rings slot 0, stats slot 0

    for (int s = 0; s < T_N; ++s) {
      gbar(barbase, epoch, grp);        // B1(s): dots(s) + stats(s) visible

      if (bid == NBLK - 1) {            // prep stats slot for step s+2
        float* so = stats + ((s + 2) & 3) * STSLOT;
        if (tid < 768) cstore(so + tid, 0.f);
      }

      if (is_gate) {
        // ---- gates: compute h(s) for (d, bs) x 16 b x 64 c ----
        const int t  = d ? (T_N - 1 - s) : s;
        const int c  = j0 + lane;
        const int gb = b0 + wv;
        const float* stp = stats + (s & 3) * STSLOT;
        float a[2][3];
#pragma unroll
        for (int k2 = 0; k2 < 2; ++k2) {
          const float* dr  = (k2 ? ahd : axd) + (s & 1) * DSLOT
                             + (size_t)(d * B_N + gb) * G3;
          const float* gam = (k2 ? gh : gx) + widx * G3;
          const float* bet = (k2 ? beh : bex) + widx * G3;
#pragma unroll
          for (int g2 = 0; g2 < 3; ++g2) {
            float v = cload(dr + g2 * H_N + c);
            const float* sl = stp + (((d * 2 + k2) * 3 + g2) * B_N + gb) * 2;
            float mu  = cload(sl)     * (1.f / 512.f);
            float var = cload(sl + 1) * (1.f / 512.f) - mu * mu;
            float inv = rsqrtf(var + EPS_LN);
            int J = g2 * H_N + c;
            a[k2][g2] = (v - mu) * inv * gam[J] + bet[J];
          }
        }
        float r = 1.f / (1.f + __expf(-(a[0][0] + a[1][0])));
        float z = 1.f / (1.f + __expf(-(a[0][1] + a[1][1])));
        float n = tanhf(a[0][2] + r * a[1][2]);
        float* hp = hbuf + (d * B_N + gb) * H_N + c;
        float hnew = (1.f - z) * n + z * cload(hp);
        cstore(hp, hnew);
        if (ph == 0) {
          cstore(&y0[(((size_t)d * T_N + t) * B_N + gb) * H_N + c], hnew);
        } else {
          out[((size_t)t * B_N + gb) * 1024 + d * H_N + c] = hnew;
        }
        if (s == T_N - 1) {
          out[OUT_HID_OFF + ((size_t)widx * B_N + gb) * H_N + c] = hnew;
        }
        gbar2_arrive(barbase2, epoch2, grp);   // publish h(s)
        if (s < T_N - 1) run_step(s + 1);      // this block's ax(s+1)
      } else if (!kind) {
        if (s < T_N - 1) run_step(s + 1);      // ax(s+1), no h dependency
      } else {
        gbar2_wait(barbase2, epoch2);          // h(s) published
        if (s < T_N - 1) {
          const float* hsrc = hbuf + (d * B_N + b0) * H_N;
#pragma unroll
          for (int q = 0; q < 4; ++q) {
            int e = (tid + q * 1024) * 2;
            U64F2 v = cload2(hsrc + e);
            int bb = e >> 9, k = e & 511;
            hl[bb * 516 + k]     = v.f[0];
            hl[bb * 516 + k + 1] = v.f[1];
          }
          __syncthreads();
          run_step(s + 1);                     // ah(s+1)
        }
      }
    }
  }
}

extern "C" void kernel_launch(void* const* d_in, const int* in_sizes, int n_in,
                              void* d_out, int out_size, void* d_ws, size_t ws_size,
                              hipStream_t stream) {
  const float* x    = (const float*)d_in[0];
  const float* h0   = (const float*)d_in[1];
  const float* Wx   = (const float*)d_in[2];
  const float* Wh   = (const float*)d_in[3];
  const float* bxp  = (const float*)d_in[4];
  const float* bhp  = (const float*)d_in[5];
  const float* gxp  = (const float*)d_in[6];
  const float* bexp = (const float*)d_in[7];
  const float* ghp  = (const float*)d_in[8];
  const float* behp = (const float*)d_in[9];
  float* out = (float*)d_out;
  float* ws  = (float*)d_ws;

  hipMemsetAsync(d_ws, 0, 16384, stream);   // barriers + 4-slot stats ring

  hipFuncSetAttribute((const void*)lngru11,
                      hipFuncAttributeMaxDynamicSharedMemorySize, LDS_BYTES);

  void* args[] = {(void*)&x, (void*)&h0, (void*)&Wx, (void*)&Wh, (void*)&bxp, (void*)&bhp,
                  (void*)&gxp, (void*)&bexp, (void*)&ghp, (void*)&behp, (void*)&out, (void*)&ws};
  hipLaunchCooperativeKernel((void*)lngru11, dim3(NBLK), dim3(NT), args, LDS_BYTES, stream);
}